// Round 5
// baseline (1220.682 us; speedup 1.0000x reference)
//
#include <hip/hip_runtime.h>

// Net_17532056502451 round 5: Gram conv, 16 waves/block, dep-free inner loop,
// lane-parallel decoder. energy[s] = ||b||^2 + sum_k y[k]*(2u[c0+k] +
// sum_j G[c0+k][c0+j] y[j]), c0=80-s. Wave w handles s === w (mod 16).
//
// ws layout (floats):
#define WS_XRES   0
#define WS_YRES   81920
#define WS_WT     163840   // Wt[c*512+f] = W_enc[f*160+c]
#define WS_G      327680   // G padded [160][164]
#define WS_U      353920   // u[160]
#define WS_BB     354080
#define WS_K      354081
#define WS_LOSS   354082   // 5 raw sq-sums (atomic)

#define GPITCH 164

// dynamic LDS float offsets
#define OFF_G    0        // 160*164 = 26240
#define OFF_YA   26240    // 4*84
#define OFF_XR   26576    // 320
#define OFF_YR   26896    // 320
#define OFF_XE   27216    // 320
#define OFF_SIM  27536    // 4*160
#define OFF_EN   28176    // 4*84
#define OFF_U    28512    // 160
#define LDS_FLOATS 28672  // 114688 bytes

__global__ void k_init(const float* __restrict__ x, const float* __restrict__ y,
                       const float* __restrict__ Wenc, float* __restrict__ ws) {
    int i = blockIdx.x * 256 + threadIdx.x;   // covers 81920
    ws[WS_XRES + i] = x[i];
    ws[WS_YRES + i] = y[i];
    int f = i / 160, c = i - f * 160;
    ws[WS_WT + c * 512 + f] = Wenc[i];
}

__device__ __forceinline__ float wave_sum(float v) {
    for (int d = 32; d > 0; d >>= 1) v += __shfl_down(v, d);
    return __shfl(v, 0);
}
__device__ __forceinline__ float wave_max(float v) {
    for (int d = 32; d > 0; d >>= 1) v = fmaxf(v, __shfl_down(v, d));
    return __shfl(v, 0);
}
__device__ __forceinline__ int wave_argmax(float v, int i) {
    for (int d = 32; d > 0; d >>= 1) {
        float v2 = __shfl_down(v, d);
        int   i2 = __shfl_down(i, d);
        if (v2 > v || (v2 == v && i2 < i)) { v = v2; i = i2; }
    }
    return __shfl(i, 0);
}

// G precompute (161 blocks): b<160 -> G row b; b==160 -> u, bb, K, zero losses.
__global__ __launch_bounds__(256)
void k_pre(const float* __restrict__ y, const float* __restrict__ benc,
           float* __restrict__ ws) {
    const int b = blockIdx.x, tid = threadIdx.x;
    const int wv = tid >> 6, lane = tid & 63;
    if (b < 160) {
        __shared__ float wr[512];
        if (tid < 128) ((float4*)wr)[tid] = ((const float4*)(ws + WS_WT + b * 512))[tid];
        __syncthreads();
        for (int cg = 0; cg < 160; cg += 4) {
            int c = cg + wv;
            const float* Wc = ws + WS_WT + c * 512;
            float a = 0.0f;
#pragma unroll
            for (int jj = 0; jj < 8; ++jj) {
                int f = lane + 64 * jj;
                a = fmaf(wr[f], Wc[f], a);
            }
            a = wave_sum(a);
            if (lane == 0) ws[WS_G + b * GPITCH + c] = a;
        }
    } else {
        for (int cg = 0; cg < 160; cg += 4) {
            int c = cg + wv;
            const float* Wc = ws + WS_WT + c * 512;
            float a = 0.0f;
#pragma unroll
            for (int jj = 0; jj < 8; ++jj) {
                int f = lane + 64 * jj;
                a = fmaf(benc[f], Wc[f], a);
            }
            a = wave_sum(a);
            if (lane == 0) ws[WS_U + c] = a;
        }
        if (wv == 0) {
            float a = 0.0f;
#pragma unroll
            for (int jj = 0; jj < 8; ++jj) {
                float bv = benc[lane + 64 * jj];
                a = fmaf(bv, bv, a);
            }
            a = wave_sum(a);
            if (lane == 0) ws[WS_BB] = a;
        }
        __shared__ int red[256];
        int cnt = 0;
        for (int i = tid; i < 81920; i += 256) cnt += (y[i] != 0.0f) ? 1 : 0;
        red[tid] = cnt;
        __syncthreads();
        for (int s = 128; s > 0; s >>= 1) {
            if (tid < s) red[tid] += red[tid + s];
            __syncthreads();
        }
        if (tid == 0) { int k = red[0]; ws[WS_K] = (float)(k < 1 ? 1 : k); }
        if (tid < 5) ws[WS_LOSS + tid] = 0.0f;
    }
}

// Quadratic form for s in {s0, s0+16, ...}: all loads of step t independent of
// t-1 (no sliding window). FMA order (t asc, q asc) bit-identical to round 4.
template<int U>
__device__ __forceinline__ void conv_run(const float* __restrict__ Glds,
                                         const float* __restrict__ yp,   // ya_l + pos*84
                                         const float* __restrict__ u_l,
                                         float* __restrict__ energy,
                                         int kl, int pos, int s0, float bbv) {
    constexpr int TMAX = (U == 0) ? 20 : 21;
    const float4* yp4 = (const float4*)yp;
    for (int s = s0; s <= 80; s += 16) {
        const int c0 = 80 - s;
        const float* gp = Glds + (c0 + 5 * kl) * GPITCH + (c0 - U);
        float acc[5] = {0.f, 0.f, 0.f, 0.f, 0.f};
#pragma unroll
        for (int t = 0; t < TMAX; ++t) {
            float4 yhi, ylo;
            if (U == 0) {
                yhi = yp4[t];
            } else {
                ylo = (t > 0) ? yp4[t - 1] : make_float4(0.f, 0.f, 0.f, 0.f);
                yhi = (t < 20) ? yp4[t] : make_float4(0.f, 0.f, 0.f, 0.f);
            }
            float4 g0 = *(const float4*)(gp + 4 * t);
            float4 g1 = *(const float4*)(gp + GPITCH + 4 * t);
            float4 g2 = *(const float4*)(gp + 2 * GPITCH + 4 * t);
            float4 g3 = *(const float4*)(gp + 3 * GPITCH + 4 * t);
            float4 g4 = *(const float4*)(gp + 4 * GPITCH + 4 * t);
            const float gq0[4] = {g0.x, g0.y, g0.z, g0.w};
            const float gq1[4] = {g1.x, g1.y, g1.z, g1.w};
            const float gq2[4] = {g2.x, g2.y, g2.z, g2.w};
            const float gq3[4] = {g3.x, g3.y, g3.z, g3.w};
            const float gq4[4] = {g4.x, g4.y, g4.z, g4.w};
            const float yh[4] = {yhi.x, yhi.y, yhi.z, yhi.w};
            float yl[4];
            if (U != 0) { yl[0] = ylo.x; yl[1] = ylo.y; yl[2] = ylo.z; yl[3] = ylo.w; }
#pragma unroll
            for (int q = 0; q < 4; ++q) {
                const int j = 4 * t + q - U;          // constant after unroll
                if (j >= 0 && j <= 79) {
                    const float yv = (q >= U) ? yh[q - U] : yl[4 + q - U];
                    acc[0] = fmaf(gq0[q], yv, acc[0]);
                    acc[1] = fmaf(gq1[q], yv, acc[1]);
                    acc[2] = fmaf(gq2[q], yv, acc[2]);
                    acc[3] = fmaf(gq3[q], yv, acc[3]);
                    acc[4] = fmaf(gq4[q], yv, acc[4]);
                }
            }
        }
        float e = 0.0f;
#pragma unroll
        for (int m = 0; m < 5; ++m) {
            const int k = 5 * kl + m;
            e += yp[k] * (acc[m] + 2.0f * u_l[c0 + k]);
        }
        e += __shfl_xor(e, 4);
        e += __shfl_xor(e, 8);
        e += __shfl_xor(e, 16);
        e += __shfl_xor(e, 32);
        if (kl == 0) energy[pos * 84 + s] = bbv + e;
    }
}

__global__ __launch_bounds__(1024, 4)
void k_iter(const float* __restrict__ yorig,
            const float* __restrict__ benc, const float* __restrict__ Wsrc,
            const float* __restrict__ bsrc,
            float* __restrict__ ws, int it) {
    float* xres = ws + WS_XRES;
    float* yres = ws + WS_YRES;
    const float* Wt = ws + WS_WT;

    extern __shared__ float lds[];
    float* Glds  = lds + OFF_G;
    float* ya_l  = lds + OFF_YA;
    float* xr    = lds + OFF_XR;
    float* yr    = lds + OFF_YR;
    float* xele  = lds + OFF_XE;
    float* simS  = lds + OFF_SIM;
    float* energy= lds + OFF_EN;
    float* u_l   = lds + OFF_U;

    __shared__ float s_ny2[4], s_sq[4], s_bb;
    __shared__ int   s_hind[4];

    const int tid  = threadIdx.x;
    const int lane = tid & 63;
    const int wv   = tid >> 6;          // 0..15
    const int base = blockIdx.x * 320;

    // ---- stage: residuals, u, bb, G ----
    if (tid < 320) { xr[tid] = xres[base + tid]; yr[tid] = yres[base + tid]; }
    if (tid >= 320 && tid < 480) u_l[tid - 320] = ws[WS_U + tid - 320];
    if (tid == 480) s_bb = ws[WS_BB];
    {
        const float4* Gg = (const float4*)(ws + WS_G);
        float4* Gl = (float4*)Glds;
        for (int idx = tid; idx < 6560; idx += 1024) Gl[idx] = Gg[idx];
    }
    __syncthreads();

    // ---- ||y||^2 per position (waves 0..3) ----
    if (wv < 4) {
        float a = yr[wv * 80 + lane];
        float v = a * a;
        if (lane < 16) { float u = yr[wv * 80 + 64 + lane]; v = fmaf(u, u, v); }
        v = wave_sum(v);
        if (lane == 0) s_ny2[wv] = v;
    }
    __syncthreads();

    // ---- cosine sim over 159 shifts x 4 positions ----
    if (tid < 636) {
        int pp = tid / 159, s = tid - pp * 159;
        int ilo = (s - 79 > 0) ? s - 79 : 0;
        int ihi = (s < 79) ? s : 79;
        const float* xp = xr + pp * 80;
        const float* yp = yr + pp * 80;
        float dot = 0.0f, nx2 = 0.0f;
        for (int i = ilo; i <= ihi; ++i) {
            float xv = xp[i];
            dot = fmaf(xv, yp[i - s + 79], dot);
            nx2 = fmaf(xv, xv, nx2);
        }
        float denom = sqrtf(nx2) * sqrtf(s_ny2[pp]);
        simS[pp * 160 + s] = (denom == 0.0f) ? 0.0f : dot / denom;
    }
    __syncthreads();

    // ---- theta argmax + softmax attention -> ya_l, xele (waves 0..3) ----
    if (wv < 4) {
        int theta;
        {
            float v = simS[wv * 160 + lane]; int i = lane;
            { float v2 = simS[wv * 160 + lane + 64]; int i2 = lane + 64;
              if (v2 > v || (v2 == v && i2 < i)) { v = v2; i = i2; } }
            if (lane < 31) {
                float v2 = simS[wv * 160 + lane + 128]; int i2 = lane + 128;
                if (v2 > v || (v2 == v && i2 < i)) { v = v2; i = i2; }
            }
            theta = wave_argmax(v, i);
        }
        const float* xp = xr + wv * 80;
        const float* yp = yr + wv * 80;
        int t0 = lane, t1 = lane + 64;
        int ix0 = theta + t0 - 79;
        float ya0 = (ix0 >= 0 && ix0 < 80) ? xp[ix0] : 0.0f;
        float z0 = ya0 * yp[t0] / 0.7f;
        float ya1 = 0.0f, z1 = -INFINITY;
        if (t1 < 80) {
            int ix1 = theta + t1 - 79;
            ya1 = (ix1 >= 0 && ix1 < 80) ? xp[ix1] : 0.0f;
            z1 = ya1 * yp[t1] / 0.7f;
        }
        float m = wave_max(fmaxf(z0, z1));
        float e0 = expf(z0 - m);
        float e1 = (t1 < 80) ? expf(z1 - m) : 0.0f;
        float S = wave_sum(e0 + e1);
        ya_l[wv * 84 + t0] = ya0 * (e0 / S);
        if (t1 < 80) ya_l[wv * 84 + t1] = ya1 * (e1 / S);
        if (lane < 4) ya_l[wv * 84 + 80 + lane] = 0.0f;
        // xele (same wave wrote ya_l; wave-coherent)
        int k0 = 79 - theta + t0;
        xele[wv * 80 + t0] = (k0 >= 0 && k0 < 80) ? ya_l[wv * 84 + k0] : 0.0f;
        if (t1 < 80) {
            int k1 = 79 - theta + t1;
            xele[wv * 80 + t1] = (k1 >= 0 && k1 < 80) ? ya_l[wv * 84 + k1] : 0.0f;
        }
    }
    __syncthreads();

    // ---- quadratic-form conv: 16 waves, s === wv (mod 16); lane = kl*4 + pos ----
    {
        const int kl = lane >> 2, pos = lane & 3;
        const float* yp = ya_l + pos * 84;
        const float bbv = s_bb;
        switch (wv & 3) {
            case 0: conv_run<0>(Glds, yp, u_l, energy, kl, pos, wv, bbv); break;
            case 1: conv_run<3>(Glds, yp, u_l, energy, kl, pos, wv, bbv); break;
            case 2: conv_run<2>(Glds, yp, u_l, energy, kl, pos, wv, bbv); break;
            default: conv_run<1>(Glds, yp, u_l, energy, kl, pos, wv, bbv); break;
        }
    }
    __syncthreads();

    // ---- h_ind argmax per position (waves 0..3) ----
    if (wv < 4) {
        float v = energy[wv * 84 + lane]; int i = lane;
        if (lane < 17) {
            float v2 = energy[wv * 84 + lane + 64]; int i2 = lane + 64;
            if (v2 > v || (v2 == v && i2 < i)) { v = v2; i = i2; }
        }
        int hind = wave_argmax(v, i);
        if (lane == 0) s_hind[wv] = hind;
    }
    __syncthreads();

    float* hselL = lds;          // overlay into dead G region
    float* xextL = lds + 2048;

    // ---- recompute h_sel rows (coalesced over f, Wt in L2) ----
    for (int t = tid; t < 2048; t += 1024) {
        int pp = t >> 9, f = t & 511;
        int cb = 80 - s_hind[pp];
        const float* Wp = Wt + cb * 512 + f;
        const float* yap = ya_l + pp * 84;
        float a0 = benc[f], a1 = 0.0f, a2 = 0.0f, a3 = 0.0f;
        for (int k = 0; k < 80; k += 4) {
            a0 = fmaf(yap[k],     Wp[k * 512],       a0);
            a1 = fmaf(yap[k + 1], Wp[(k + 1) * 512], a1);
            a2 = fmaf(yap[k + 2], Wp[(k + 2) * 512], a2);
            a3 = fmaf(yap[k + 3], Wp[(k + 3) * 512], a3);
        }
        hselL[t] = (a0 + a1) + (a2 + a3);
    }
    __syncthreads();

    // ---- decoder: lane-parallel dot per output, original W_src layout ----
    for (int r = 0; r < 40; ++r) {
        int oid = wv * 40 + r;                 // 640 outputs / 16 waves
        int pp = oid / 160, o = oid - pp * 160;
        const float* Wr = Wsrc + o * 512;
        const float* hp = hselL + pp * 512;
        float a = 0.0f;
#pragma unroll
        for (int jj = 0; jj < 8; ++jj) {
            int f = lane + 64 * jj;
            a = fmaf(hp[f], Wr[f], a);
        }
        a = wave_sum(a);
        if (lane == 0) xextL[oid] = a + bsrc[o];
    }
    __syncthreads();

    // ---- loss + residual update per position (waves 0..3) ----
    if (wv < 4) {
        int hd = s_hind[wv];
        int t0 = lane, t1 = lane + 64;
        float sq;
        {
            float yele = xextL[wv * 160 + 80 - hd + t0];
            float yv = yr[wv * 80 + t0];
            float keep = (yorig[base + wv * 80 + t0] != 0.0f) ? 1.0f : 0.0f;
            float d = yele - yv;
            sq = d * d * keep;
            yres[base + wv * 80 + t0] = yv - yele;
            xres[base + wv * 80 + t0] = xr[wv * 80 + t0] - xele[wv * 80 + t0];
        }
        if (t1 < 80) {
            float yele = xextL[wv * 160 + 80 - hd + t1];
            float yv = yr[wv * 80 + t1];
            float keep = (yorig[base + wv * 80 + t1] != 0.0f) ? 1.0f : 0.0f;
            float d = yele - yv;
            sq = fmaf(d * keep, d, sq);
            yres[base + wv * 80 + t1] = yv - yele;
            xres[base + wv * 80 + t1] = xr[wv * 80 + t1] - xele[wv * 80 + t1];
        }
        sq = wave_sum(sq);
        if (lane == 0) s_sq[wv] = sq;
    }
    __syncthreads();
    if (tid == 0)
        atomicAdd(&ws[WS_LOSS + it], (s_sq[0] + s_sq[1]) + (s_sq[2] + s_sq[3]));
}

__global__ void k_final(const float* __restrict__ ws, float* __restrict__ out) {
    float K = ws[WS_K];
    out[0] = (ws[WS_LOSS] + ws[WS_LOSS + 1] + ws[WS_LOSS + 2] +
              ws[WS_LOSS + 3] + ws[WS_LOSS + 4]) / (K * 5.0f);
}

extern "C" void kernel_launch(void* const* d_in, const int* in_sizes, int n_in,
                              void* d_out, int out_size, void* d_ws, size_t ws_size,
                              hipStream_t stream) {
    const float* x    = (const float*)d_in[0];
    const float* y    = (const float*)d_in[1];
    const float* Wenc = (const float*)d_in[2];
    const float* benc = (const float*)d_in[3];
    const float* Wsrc = (const float*)d_in[4];
    const float* bsrc = (const float*)d_in[5];
    float* ws  = (float*)d_ws;
    float* out = (float*)d_out;

    (void)hipFuncSetAttribute((const void*)k_iter,
                              hipFuncAttributeMaxDynamicSharedMemorySize,
                              LDS_FLOATS * 4);

    k_init<<<320, 256, 0, stream>>>(x, y, Wenc, ws);
    k_pre<<<161, 256, 0, stream>>>(y, benc, ws);
    for (int it = 0; it < 5; ++it)
        k_iter<<<256, 1024, LDS_FLOATS * 4, stream>>>(y, benc, Wsrc, bsrc, ws, it);
    k_final<<<1, 1, 0, stream>>>(ws, out);
}

// Round 7
// 630.422 us; speedup vs baseline: 1.9363x; 1.9363x over previous
//
#include <hip/hip_runtime.h>

// Net_17532056502451 round 6b: per-phase kernels (compile fix: conv_s ws non-const).
// k_sel  (1024 blks x 128): sim + theta + softmax -> ya, xele
// k_conv (648 blks x 256):  energy[p][s] via Gram quadratic form, G_s (80x80) in LDS
// k_dec  (1024 blks x 256): h_ind argmax + hsel + decoder + loss + residual update
//
// ws layout (floats):
#define WS_XRES   0
#define WS_YRES   81920
#define WS_WT     163840   // Wt[c*512+f] = W_enc[f*160+c]
#define WS_G      327680   // G padded [160][164]
#define WS_U      353920   // u[160]
#define WS_BB     354080
#define WS_K      354081
#define WS_LOSS   354082   // 5 raw sq-sums (atomic); pad to 354088
#define WS_YA     354088   // [1024][88]
#define WS_XELE   444200   // [1024][80]
#define WS_EN     526120   // [1024][84]
// total 612136 floats = 2.34 MB

#define GPITCH 164
#define GP2    84

__global__ void k_init(const float* __restrict__ x, const float* __restrict__ y,
                       const float* __restrict__ Wenc, float* __restrict__ ws) {
    int i = blockIdx.x * 256 + threadIdx.x;   // covers 81920
    ws[WS_XRES + i] = x[i];
    ws[WS_YRES + i] = y[i];
    int f = i / 160, c = i - f * 160;
    ws[WS_WT + c * 512 + f] = Wenc[i];
}

__device__ __forceinline__ float wave_sum(float v) {
    for (int d = 32; d > 0; d >>= 1) v += __shfl_down(v, d);
    return __shfl(v, 0);
}
__device__ __forceinline__ float wave_max(float v) {
    for (int d = 32; d > 0; d >>= 1) v = fmaxf(v, __shfl_down(v, d));
    return __shfl(v, 0);
}
__device__ __forceinline__ int wave_argmax(float v, int i) {
    for (int d = 32; d > 0; d >>= 1) {
        float v2 = __shfl_down(v, d);
        int   i2 = __shfl_down(i, d);
        if (v2 > v || (v2 == v && i2 < i)) { v = v2; i = i2; }
    }
    return __shfl(i, 0);
}

// G precompute (161 blocks): b<160 -> G row b; b==160 -> u, bb, K, zero losses.
__global__ __launch_bounds__(256)
void k_pre(const float* __restrict__ y, const float* __restrict__ benc,
           float* __restrict__ ws) {
    const int b = blockIdx.x, tid = threadIdx.x;
    const int wv = tid >> 6, lane = tid & 63;
    if (b < 160) {
        __shared__ float wr[512];
        if (tid < 128) ((float4*)wr)[tid] = ((const float4*)(ws + WS_WT + b * 512))[tid];
        __syncthreads();
        for (int cg = 0; cg < 160; cg += 4) {
            int c = cg + wv;
            const float* Wc = ws + WS_WT + c * 512;
            float a = 0.0f;
#pragma unroll
            for (int jj = 0; jj < 8; ++jj) {
                int f = lane + 64 * jj;
                a = fmaf(wr[f], Wc[f], a);
            }
            a = wave_sum(a);
            if (lane == 0) ws[WS_G + b * GPITCH + c] = a;
        }
    } else {
        for (int cg = 0; cg < 160; cg += 4) {
            int c = cg + wv;
            const float* Wc = ws + WS_WT + c * 512;
            float a = 0.0f;
#pragma unroll
            for (int jj = 0; jj < 8; ++jj) {
                int f = lane + 64 * jj;
                a = fmaf(benc[f], Wc[f], a);
            }
            a = wave_sum(a);
            if (lane == 0) ws[WS_U + c] = a;
        }
        if (wv == 0) {
            float a = 0.0f;
#pragma unroll
            for (int jj = 0; jj < 8; ++jj) {
                float bv = benc[lane + 64 * jj];
                a = fmaf(bv, bv, a);
            }
            a = wave_sum(a);
            if (lane == 0) ws[WS_BB] = a;
        }
        __shared__ int red[256];
        int cnt = 0;
        for (int i = tid; i < 81920; i += 256) cnt += (y[i] != 0.0f) ? 1 : 0;
        red[tid] = cnt;
        __syncthreads();
        for (int s = 128; s > 0; s >>= 1) {
            if (tid < s) red[tid] += red[tid + s];
            __syncthreads();
        }
        if (tid == 0) { int k = red[0]; ws[WS_K] = (float)(k < 1 ? 1 : k); }
        if (tid < 5) ws[WS_LOSS + tid] = 0.0f;
    }
}

// ---------------- k_sel: selector + softmax per position ----------------
__global__ __launch_bounds__(128)
void k_sel(float* __restrict__ ws) {
    const int p = blockIdx.x, tid = threadIdx.x, lane = tid & 63;
    const int base = p * 80;
    __shared__ float xr[80], yr[80], simS[160], ya[88];
    __shared__ float s_ny2;

    if (tid < 80) { xr[tid] = ws[WS_XRES + base + tid]; yr[tid] = ws[WS_YRES + base + tid]; }
    __syncthreads();

    if (tid < 64) {
        float a = yr[lane];
        float v = a * a;
        if (lane < 16) { float u = yr[64 + lane]; v = fmaf(u, u, v); }
        v = wave_sum(v);
        if (lane == 0) s_ny2 = v;
    }
    __syncthreads();

    for (int s = tid; s < 159; s += 128) {
        int ilo = (s - 79 > 0) ? s - 79 : 0;
        int ihi = (s < 79) ? s : 79;
        float dot = 0.0f, nx2 = 0.0f;
        for (int i = ilo; i <= ihi; ++i) {
            float xv = xr[i];
            dot = fmaf(xv, yr[i - s + 79], dot);
            nx2 = fmaf(xv, xv, nx2);
        }
        float denom = sqrtf(nx2) * sqrtf(s_ny2);
        simS[s] = (denom == 0.0f) ? 0.0f : dot / denom;
    }
    __syncthreads();

    if (tid < 64) {
        int theta;
        {
            float v = simS[lane]; int i = lane;
            { float v2 = simS[lane + 64]; int i2 = lane + 64;
              if (v2 > v || (v2 == v && i2 < i)) { v = v2; i = i2; } }
            if (lane < 31) {
                float v2 = simS[lane + 128]; int i2 = lane + 128;
                if (v2 > v || (v2 == v && i2 < i)) { v = v2; i = i2; }
            }
            theta = wave_argmax(v, i);
        }
        int t0 = lane, t1 = lane + 64;
        int ix0 = theta + t0 - 79;
        float ya0 = (ix0 >= 0 && ix0 < 80) ? xr[ix0] : 0.0f;
        float z0 = ya0 * yr[t0] / 0.7f;
        float ya1 = 0.0f, z1 = -INFINITY;
        if (t1 < 80) {
            int ix1 = theta + t1 - 79;
            ya1 = (ix1 >= 0 && ix1 < 80) ? xr[ix1] : 0.0f;
            z1 = ya1 * yr[t1] / 0.7f;
        }
        float m = wave_max(fmaxf(z0, z1));
        float e0 = expf(z0 - m);
        float e1 = (t1 < 80) ? expf(z1 - m) : 0.0f;
        float S = wave_sum(e0 + e1);
        ya[t0] = ya0 * (e0 / S);
        if (t1 < 80) ya[t1] = ya1 * (e1 / S);
        if (lane < 8) ya[80 + lane] = 0.0f;
        // write ya to ws
        ws[WS_YA + p * 88 + t0] = ya[t0];
        if (t1 < 80) ws[WS_YA + p * 88 + t1] = ya[t1];
        if (lane < 8) ws[WS_YA + p * 88 + 80 + lane] = 0.0f;
        // xele
        int k0 = 79 - theta + t0;
        ws[WS_XELE + base + t0] = (k0 >= 0 && k0 < 80) ? ya[k0] : 0.0f;
        if (t1 < 80) {
            int k1 = 79 - theta + t1;
            ws[WS_XELE + base + t1] = (k1 >= 0 && k1 < 80) ? ya[k1] : 0.0f;
        }
    }
}

// ---------------- k_conv: energy via Gram quadratic form ----------------
// block = (s, 128-position group); G_s staged in LDS [80][84].
template<int U>
__device__ __forceinline__ void conv_s(const float* __restrict__ Gs,
                                       float* __restrict__ ws,
                                       int s, int c0, int pbase_w,
                                       int kl, int pos, float bbv) {
    constexpr int TMAX = (U == 0) ? 20 : 21;
    const float* u_g = ws + WS_U;
    const float* gp = Gs + 5 * kl * GP2;
    for (int g = 0; g < 8; ++g) {
        const int p = pbase_w + g * 4 + pos;
        const float* yp = ws + WS_YA + p * 88;
        const float4* yp4 = (const float4*)yp;
        float acc[5] = {0.f, 0.f, 0.f, 0.f, 0.f};
#pragma unroll
        for (int t = 0; t < TMAX; ++t) {
            float4 yhi, ylo;
            if (U == 0) {
                yhi = yp4[t];
            } else {
                ylo = (t > 0) ? yp4[t - 1] : make_float4(0.f, 0.f, 0.f, 0.f);
                yhi = (t < 20) ? yp4[t] : make_float4(0.f, 0.f, 0.f, 0.f);
            }
            float4 g0 = *(const float4*)(gp + 4 * t);
            float4 g1 = *(const float4*)(gp + GP2 + 4 * t);
            float4 g2 = *(const float4*)(gp + 2 * GP2 + 4 * t);
            float4 g3 = *(const float4*)(gp + 3 * GP2 + 4 * t);
            float4 g4 = *(const float4*)(gp + 4 * GP2 + 4 * t);
            const float gq0[4] = {g0.x, g0.y, g0.z, g0.w};
            const float gq1[4] = {g1.x, g1.y, g1.z, g1.w};
            const float gq2[4] = {g2.x, g2.y, g2.z, g2.w};
            const float gq3[4] = {g3.x, g3.y, g3.z, g3.w};
            const float gq4[4] = {g4.x, g4.y, g4.z, g4.w};
            const float yh[4] = {yhi.x, yhi.y, yhi.z, yhi.w};
            float yl[4];
            if (U != 0) { yl[0] = ylo.x; yl[1] = ylo.y; yl[2] = ylo.z; yl[3] = ylo.w; }
#pragma unroll
            for (int q = 0; q < 4; ++q) {
                const int j = 4 * t + q - U;
                if (j >= 0 && j <= 79) {
                    const float yv = (q >= U) ? yh[q - U] : yl[4 + q - U];
                    acc[0] = fmaf(gq0[q], yv, acc[0]);
                    acc[1] = fmaf(gq1[q], yv, acc[1]);
                    acc[2] = fmaf(gq2[q], yv, acc[2]);
                    acc[3] = fmaf(gq3[q], yv, acc[3]);
                    acc[4] = fmaf(gq4[q], yv, acc[4]);
                }
            }
        }
        float e = 0.0f;
#pragma unroll
        for (int m = 0; m < 5; ++m) {
            const int k = 5 * kl + m;
            e += yp[k] * (acc[m] + 2.0f * u_g[c0 + k]);
        }
        e += __shfl_xor(e, 4);
        e += __shfl_xor(e, 8);
        e += __shfl_xor(e, 16);
        e += __shfl_xor(e, 32);
        if (kl == 0) ws[WS_EN + p * 84 + s] = bbv + e;
    }
}

__global__ __launch_bounds__(256)
void k_conv(float* __restrict__ ws) {
    const int bid = blockIdx.x;      // 81 * 8
    const int s   = bid >> 3;
    const int pg  = bid & 7;
    const int c0  = 80 - s;
    const int U   = c0 & 3;
    const int tid = threadIdx.x;

    __shared__ __align__(16) float Gs[80 * GP2];   // 26.9 KB
    {
        const float* src = ws + WS_G + c0 * GPITCH + (c0 - U);
        for (int idx = tid; idx < 1680; idx += 256) {      // 80 rows x 21 float4
            int r = idx / 21, cc = idx - r * 21;
            float4 v = *(const float4*)(src + r * GPITCH + 4 * cc);
            *(float4*)(Gs + r * GP2 + 4 * cc) = v;
        }
    }
    __syncthreads();

    const int lane = tid & 63, wv = tid >> 6;
    const int kl = lane >> 2, pos = lane & 3;
    const int pbase_w = pg * 128 + wv * 32;
    const float bbv = ws[WS_BB];
    switch (U) {
        case 0: conv_s<0>(Gs, ws, s, c0, pbase_w, kl, pos, bbv); break;
        case 1: conv_s<1>(Gs, ws, s, c0, pbase_w, kl, pos, bbv); break;
        case 2: conv_s<2>(Gs, ws, s, c0, pbase_w, kl, pos, bbv); break;
        default: conv_s<3>(Gs, ws, s, c0, pbase_w, kl, pos, bbv); break;
    }
}

// ---------------- k_dec: argmax + hsel + decoder + loss ----------------
__global__ __launch_bounds__(256)
void k_dec(const float* __restrict__ yorig, const float* __restrict__ benc,
           const float* __restrict__ Wsrc, const float* __restrict__ bsrc,
           float* __restrict__ ws, int it) {
    const int p = blockIdx.x, tid = threadIdx.x;
    const int lane = tid & 63, wv = tid >> 6;
    const int base = p * 80;

    __shared__ float ya_l[84], yr_l[80], hsel[512], xext[160];
    __shared__ int s_hind;

    if (tid < 84) ya_l[tid] = ws[WS_YA + p * 88 + tid];
    if (tid >= 128 && tid < 208) yr_l[tid - 128] = ws[WS_YRES + base + tid - 128];
    __syncthreads();

    if (tid < 64) {
        float v = ws[WS_EN + p * 84 + lane]; int i = lane;
        if (lane < 17) {
            float v2 = ws[WS_EN + p * 84 + lane + 64]; int i2 = lane + 64;
            if (v2 > v || (v2 == v && i2 < i)) { v = v2; i = i2; }
        }
        int hind = wave_argmax(v, i);
        if (lane == 0) s_hind = hind;
    }
    __syncthreads();
    const int hd = s_hind;

    // hsel (coalesced over f, Wt in L2)
    {
        const int cb = 80 - hd;
        for (int f = tid; f < 512; f += 256) {
            const float* Wp = ws + WS_WT + cb * 512 + f;
            float a0 = benc[f], a1 = 0.0f, a2 = 0.0f, a3 = 0.0f;
            for (int k = 0; k < 80; k += 4) {
                a0 = fmaf(ya_l[k],     Wp[k * 512],       a0);
                a1 = fmaf(ya_l[k + 1], Wp[(k + 1) * 512], a1);
                a2 = fmaf(ya_l[k + 2], Wp[(k + 2) * 512], a2);
                a3 = fmaf(ya_l[k + 3], Wp[(k + 3) * 512], a3);
            }
            hsel[f] = (a0 + a1) + (a2 + a3);
        }
    }
    __syncthreads();

    // decoder: 4 waves x 40 outputs, lane-parallel dots
    for (int r = 0; r < 40; ++r) {
        int o = wv * 40 + r;
        const float* Wr = Wsrc + o * 512;
        float a = 0.0f;
#pragma unroll
        for (int jj = 0; jj < 8; ++jj) {
            int f = lane + 64 * jj;
            a = fmaf(hsel[f], Wr[f], a);
        }
        a = wave_sum(a);
        if (lane == 0) xext[o] = a + bsrc[o];
    }
    __syncthreads();

    // loss + residual update (wave 0)
    if (tid < 64) {
        int t0 = lane, t1 = lane + 64;
        float sq;
        {
            float yele = xext[80 - hd + t0];
            float yv = yr_l[t0];
            float keep = (yorig[base + t0] != 0.0f) ? 1.0f : 0.0f;
            float d = yele - yv;
            sq = d * d * keep;
            ws[WS_YRES + base + t0] = yv - yele;
            ws[WS_XRES + base + t0] = ws[WS_XRES + base + t0] - ws[WS_XELE + base + t0];
        }
        if (t1 < 80) {
            float yele = xext[80 - hd + t1];
            float yv = yr_l[t1];
            float keep = (yorig[base + t1] != 0.0f) ? 1.0f : 0.0f;
            float d = yele - yv;
            sq = fmaf(d * keep, d, sq);
            ws[WS_YRES + base + t1] = yv - yele;
            ws[WS_XRES + base + t1] = ws[WS_XRES + base + t1] - ws[WS_XELE + base + t1];
        }
        sq = wave_sum(sq);
        if (lane == 0) atomicAdd(&ws[WS_LOSS + it], sq);
    }
}

__global__ void k_final(const float* __restrict__ ws, float* __restrict__ out) {
    float K = ws[WS_K];
    out[0] = (ws[WS_LOSS] + ws[WS_LOSS + 1] + ws[WS_LOSS + 2] +
              ws[WS_LOSS + 3] + ws[WS_LOSS + 4]) / (K * 5.0f);
}

extern "C" void kernel_launch(void* const* d_in, const int* in_sizes, int n_in,
                              void* d_out, int out_size, void* d_ws, size_t ws_size,
                              hipStream_t stream) {
    const float* x    = (const float*)d_in[0];
    const float* y    = (const float*)d_in[1];
    const float* Wenc = (const float*)d_in[2];
    const float* benc = (const float*)d_in[3];
    const float* Wsrc = (const float*)d_in[4];
    const float* bsrc = (const float*)d_in[5];
    float* ws  = (float*)d_ws;
    float* out = (float*)d_out;

    k_init<<<320, 256, 0, stream>>>(x, y, Wenc, ws);
    k_pre<<<161, 256, 0, stream>>>(y, benc, ws);
    for (int it = 0; it < 5; ++it) {
        k_sel<<<1024, 128, 0, stream>>>(ws);
        k_conv<<<648, 256, 0, stream>>>(ws);
        k_dec<<<1024, 256, 0, stream>>>(y, benc, Wsrc, bsrc, ws, it);
    }
    k_final<<<1, 1, 0, stream>>>(ws, out);
}

// Round 8
// 505.939 us; speedup vs baseline: 2.4127x; 1.2460x over previous
//
#include <hip/hip_runtime.h>

// Net_17532056502451 round 8: fused dec+sel, coalesced G precompute, conv pg=16.
// ws layout (floats):
#define WS_XRES   0
#define WS_YRES   81920
#define WS_WT     163840   // Wt[c*512+f] = W_enc[f*160+c]
#define WS_WST    245760   // Wst[f*160+o] = W_src[o*512+f]
#define WS_G      327680   // G padded [160][164]
#define WS_U      353920   // u[160]
#define WS_BB     354080
#define WS_K      354081
#define WS_LOSS   354082   // 5 raw sq-sums (atomic)
#define WS_YA     354088   // [1024][88]
#define WS_XELE   444200   // [1024][80]
#define WS_EN     526120   // [1024][84]

#define GPITCH 164
#define GP2    84

__global__ void k_init(const float* __restrict__ x, const float* __restrict__ y,
                       const float* __restrict__ Wenc, const float* __restrict__ Wsrc,
                       float* __restrict__ ws) {
    int i = blockIdx.x * 256 + threadIdx.x;   // covers 81920
    ws[WS_XRES + i] = x[i];
    ws[WS_YRES + i] = y[i];
    int f = i / 160, c = i - f * 160;
    ws[WS_WT + c * 512 + f] = Wenc[i];
    int o = i >> 9, f2 = i & 511;
    ws[WS_WST + f2 * 160 + o] = Wsrc[i];
    if (i == 0) {
        ws[WS_K] = 0.0f;
        for (int t = 0; t < 5; ++t) ws[WS_LOSS + t] = 0.0f;
    }
}

__device__ __forceinline__ float wave_sum(float v) {
    for (int d = 32; d > 0; d >>= 1) v += __shfl_down(v, d);
    return __shfl(v, 0);
}
__device__ __forceinline__ float wave_max(float v) {
    for (int d = 32; d > 0; d >>= 1) v = fmaxf(v, __shfl_down(v, d));
    return __shfl(v, 0);
}
__device__ __forceinline__ int wave_argmax(float v, int i) {
    for (int d = 32; d > 0; d >>= 1) {
        float v2 = __shfl_down(v, d);
        int   i2 = __shfl_down(i, d);
        if (v2 > v || (v2 == v && i2 < i)) { v = v2; i = i2; }
    }
    return __shfl(i, 0);
}

// y-nonzero count, 320 blocks
__global__ __launch_bounds__(256)
void k_cnt(const float* __restrict__ y, float* __restrict__ ws) {
    __shared__ int red[256];
    int tid = threadIdx.x;
    int i = blockIdx.x * 256 + tid;
    red[tid] = (y[i] != 0.0f) ? 1 : 0;
    __syncthreads();
    for (int s = 128; s > 0; s >>= 1) {
        if (tid < s) red[tid] += red[tid + s];
        __syncthreads();
    }
    if (tid == 0) atomicAdd(&ws[WS_K], (float)red[0]);
}

// G rows (b<160) / u+bb (b==160): per-thread column, coalesced Wenc reads.
__global__ __launch_bounds__(256)
void k_pre(const float* __restrict__ Wenc, const float* __restrict__ benc,
           float* __restrict__ ws) {
    const int b = blockIdx.x, tid = threadIdx.x;
    __shared__ float wr[512];
    if (b < 160) {
        wr[tid] = ws[WS_WT + b * 512 + tid];
        wr[tid + 256] = ws[WS_WT + b * 512 + 256 + tid];
        __syncthreads();
        if (tid < 160) {
            const float* Wc = Wenc + tid;
            float a0 = 0.f, a1 = 0.f, a2 = 0.f, a3 = 0.f;
            for (int f = 0; f < 512; f += 4) {
                a0 = fmaf(wr[f],     Wc[f * 160],       a0);
                a1 = fmaf(wr[f + 1], Wc[(f + 1) * 160], a1);
                a2 = fmaf(wr[f + 2], Wc[(f + 2) * 160], a2);
                a3 = fmaf(wr[f + 3], Wc[(f + 3) * 160], a3);
            }
            ws[WS_G + b * GPITCH + tid] = (a0 + a1) + (a2 + a3);
        }
    } else {
        wr[tid] = benc[tid];
        wr[tid + 256] = benc[tid + 256];
        __syncthreads();
        if (tid < 160) {
            const float* Wc = Wenc + tid;
            float a0 = 0.f, a1 = 0.f, a2 = 0.f, a3 = 0.f;
            for (int f = 0; f < 512; f += 4) {
                a0 = fmaf(wr[f],     Wc[f * 160],       a0);
                a1 = fmaf(wr[f + 1], Wc[(f + 1) * 160], a1);
                a2 = fmaf(wr[f + 2], Wc[(f + 2) * 160], a2);
                a3 = fmaf(wr[f + 3], Wc[(f + 3) * 160], a3);
            }
            ws[WS_U + tid] = (a0 + a1) + (a2 + a3);
        }
        if (tid < 64) {
            float a = 0.0f;
#pragma unroll
            for (int jj = 0; jj < 8; ++jj) {
                float bv = wr[tid + 64 * jj];
                a = fmaf(bv, bv, a);
            }
            a = wave_sum(a);
            if (tid == 0) ws[WS_BB] = a;
        }
    }
}

// ---------------- k_sel: initial selector + softmax per position ----------------
__global__ __launch_bounds__(128)
void k_sel(float* __restrict__ ws) {
    const int p = blockIdx.x, tid = threadIdx.x, lane = tid & 63;
    const int base = p * 80;
    __shared__ float xr[80], yr[80], simS[160], ya[88];
    __shared__ float s_ny2;

    if (tid < 80) { xr[tid] = ws[WS_XRES + base + tid]; yr[tid] = ws[WS_YRES + base + tid]; }
    __syncthreads();

    if (tid < 64) {
        float a = yr[lane];
        float v = a * a;
        if (lane < 16) { float u = yr[64 + lane]; v = fmaf(u, u, v); }
        v = wave_sum(v);
        if (lane == 0) s_ny2 = v;
    }
    __syncthreads();

    for (int s = tid; s < 159; s += 128) {
        int ilo = (s - 79 > 0) ? s - 79 : 0;
        int ihi = (s < 79) ? s : 79;
        float dot = 0.0f, nx2 = 0.0f;
        for (int i = ilo; i <= ihi; ++i) {
            float xv = xr[i];
            dot = fmaf(xv, yr[i - s + 79], dot);
            nx2 = fmaf(xv, xv, nx2);
        }
        float denom = sqrtf(nx2) * sqrtf(s_ny2);
        simS[s] = (denom == 0.0f) ? 0.0f : dot / denom;
    }
    __syncthreads();

    if (tid < 64) {
        int theta;
        {
            float v = simS[lane]; int i = lane;
            { float v2 = simS[lane + 64]; int i2 = lane + 64;
              if (v2 > v || (v2 == v && i2 < i)) { v = v2; i = i2; } }
            if (lane < 31) {
                float v2 = simS[lane + 128]; int i2 = lane + 128;
                if (v2 > v || (v2 == v && i2 < i)) { v = v2; i = i2; }
            }
            theta = wave_argmax(v, i);
        }
        int t0 = lane, t1 = lane + 64;
        int ix0 = theta + t0 - 79;
        float ya0 = (ix0 >= 0 && ix0 < 80) ? xr[ix0] : 0.0f;
        float z0 = ya0 * yr[t0] / 0.7f;
        float ya1 = 0.0f, z1 = -INFINITY;
        if (t1 < 80) {
            int ix1 = theta + t1 - 79;
            ya1 = (ix1 >= 0 && ix1 < 80) ? xr[ix1] : 0.0f;
            z1 = ya1 * yr[t1] / 0.7f;
        }
        float m = wave_max(fmaxf(z0, z1));
        float e0 = expf(z0 - m);
        float e1 = (t1 < 80) ? expf(z1 - m) : 0.0f;
        float S = wave_sum(e0 + e1);
        ya[t0] = ya0 * (e0 / S);
        if (t1 < 80) ya[t1] = ya1 * (e1 / S);
        ws[WS_YA + p * 88 + t0] = ya[t0];
        if (t1 < 80) ws[WS_YA + p * 88 + t1] = ya[t1];
        if (lane < 8) ws[WS_YA + p * 88 + 80 + lane] = 0.0f;
        int k0 = 79 - theta + t0;
        ws[WS_XELE + base + t0] = (k0 >= 0 && k0 < 80) ? ya[k0] : 0.0f;
        if (t1 < 80) {
            int k1 = 79 - theta + t1;
            ws[WS_XELE + base + t1] = (k1 >= 0 && k1 < 80) ? ya[k1] : 0.0f;
        }
    }
}

// ---------------- k_conv: energy via Gram quadratic form ----------------
template<int U>
__device__ __forceinline__ void conv_s(const float* __restrict__ Gs,
                                       float* __restrict__ ws,
                                       int s, int c0, int pbase_w,
                                       int kl, int pos, float bbv) {
    constexpr int TMAX = (U == 0) ? 20 : 21;
    const float* u_g = ws + WS_U;
    const float* gp = Gs + 5 * kl * GP2;
    for (int g = 0; g < 4; ++g) {
        const int p = pbase_w + g * 4 + pos;
        const float* yp = ws + WS_YA + p * 88;
        const float4* yp4 = (const float4*)yp;
        float acc[5] = {0.f, 0.f, 0.f, 0.f, 0.f};
#pragma unroll
        for (int t = 0; t < TMAX; ++t) {
            float4 yhi, ylo;
            if (U == 0) {
                yhi = yp4[t];
            } else {
                ylo = (t > 0) ? yp4[t - 1] : make_float4(0.f, 0.f, 0.f, 0.f);
                yhi = (t < 20) ? yp4[t] : make_float4(0.f, 0.f, 0.f, 0.f);
            }
            float4 g0 = *(const float4*)(gp + 4 * t);
            float4 g1 = *(const float4*)(gp + GP2 + 4 * t);
            float4 g2 = *(const float4*)(gp + 2 * GP2 + 4 * t);
            float4 g3 = *(const float4*)(gp + 3 * GP2 + 4 * t);
            float4 g4 = *(const float4*)(gp + 4 * GP2 + 4 * t);
            const float gq0[4] = {g0.x, g0.y, g0.z, g0.w};
            const float gq1[4] = {g1.x, g1.y, g1.z, g1.w};
            const float gq2[4] = {g2.x, g2.y, g2.z, g2.w};
            const float gq3[4] = {g3.x, g3.y, g3.z, g3.w};
            const float gq4[4] = {g4.x, g4.y, g4.z, g4.w};
            const float yh[4] = {yhi.x, yhi.y, yhi.z, yhi.w};
            float yl[4];
            if (U != 0) { yl[0] = ylo.x; yl[1] = ylo.y; yl[2] = ylo.z; yl[3] = ylo.w; }
#pragma unroll
            for (int q = 0; q < 4; ++q) {
                const int j = 4 * t + q - U;
                if (j >= 0 && j <= 79) {
                    const float yv = (q >= U) ? yh[q - U] : yl[4 + q - U];
                    acc[0] = fmaf(gq0[q], yv, acc[0]);
                    acc[1] = fmaf(gq1[q], yv, acc[1]);
                    acc[2] = fmaf(gq2[q], yv, acc[2]);
                    acc[3] = fmaf(gq3[q], yv, acc[3]);
                    acc[4] = fmaf(gq4[q], yv, acc[4]);
                }
            }
        }
        float e = 0.0f;
#pragma unroll
        for (int m = 0; m < 5; ++m) {
            const int k = 5 * kl + m;
            e += yp[k] * (acc[m] + 2.0f * u_g[c0 + k]);
        }
        e += __shfl_xor(e, 4);
        e += __shfl_xor(e, 8);
        e += __shfl_xor(e, 16);
        e += __shfl_xor(e, 32);
        if (kl == 0) ws[WS_EN + p * 84 + s] = bbv + e;
    }
}

__global__ __launch_bounds__(256)
void k_conv(float* __restrict__ ws) {
    const int bid = blockIdx.x;      // 81 * 16
    const int s   = bid >> 4;
    const int pg  = bid & 15;
    const int c0  = 80 - s;
    const int U   = c0 & 3;
    const int tid = threadIdx.x;

    __shared__ __align__(16) float Gs[80 * GP2];   // 26.9 KB
    {
        const float* src = ws + WS_G + c0 * GPITCH + (c0 - U);
        for (int idx = tid; idx < 1680; idx += 256) {      // 80 rows x 21 float4
            int r = idx / 21, cc = idx - r * 21;
            float4 v = *(const float4*)(src + r * GPITCH + 4 * cc);
            *(float4*)(Gs + r * GP2 + 4 * cc) = v;
        }
    }
    __syncthreads();

    const int lane = tid & 63, wv = tid >> 6;
    const int kl = lane >> 2, pos = lane & 3;
    const int pbase_w = pg * 64 + wv * 16;
    const float bbv = ws[WS_BB];
    switch (U) {
        case 0: conv_s<0>(Gs, ws, s, c0, pbase_w, kl, pos, bbv); break;
        case 1: conv_s<1>(Gs, ws, s, c0, pbase_w, kl, pos, bbv); break;
        case 2: conv_s<2>(Gs, ws, s, c0, pbase_w, kl, pos, bbv); break;
        default: conv_s<3>(Gs, ws, s, c0, pbase_w, kl, pos, bbv); break;
    }
}

// -------- k_fuse: argmax + hsel + decoder + loss + residuals + next-iter sel --------
__global__ __launch_bounds__(256)
void k_fuse(const float* __restrict__ yorig, const float* __restrict__ benc,
            const float* __restrict__ bsrc,
            float* __restrict__ ws, int it) {
    const int p = blockIdx.x, tid = threadIdx.x;
    const int lane = tid & 63, wv = tid >> 6;
    const int base = p * 80;

    __shared__ float ya_l[84], yr_l[80], xr_l[80], xele_l[80];
    __shared__ float hsel[512], xext[160];
    __shared__ float yr2[80], xr2[80], simS[160], ya_n[88];
    __shared__ float s_ny2;
    __shared__ int s_hind;

    if (tid < 84) ya_l[tid] = ws[WS_YA + p * 88 + tid];
    if (tid >= 96 && tid < 176) yr_l[tid - 96] = ws[WS_YRES + base + tid - 96];
    if (tid >= 176) xr_l[tid - 176] = ws[WS_XRES + base + tid - 176];
    if (tid < 80) xele_l[tid] = ws[WS_XELE + base + tid];
    __syncthreads();

    if (tid < 64) {
        float v = ws[WS_EN + p * 84 + lane]; int i = lane;
        if (lane < 17) {
            float v2 = ws[WS_EN + p * 84 + lane + 64]; int i2 = lane + 64;
            if (v2 > v || (v2 == v && i2 < i)) { v = v2; i = i2; }
        }
        int hind = wave_argmax(v, i);
        if (lane == 0) s_hind = hind;
    }
    __syncthreads();
    const int hd = s_hind;

    // hsel (coalesced over f, Wt in L2)
    {
        const int cb = 80 - hd;
        for (int f = tid; f < 512; f += 256) {
            const float* Wp = ws + WS_WT + cb * 512 + f;
            float a0 = benc[f], a1 = 0.0f, a2 = 0.0f, a3 = 0.0f;
            for (int k = 0; k < 80; k += 4) {
                a0 = fmaf(ya_l[k],     Wp[k * 512],       a0);
                a1 = fmaf(ya_l[k + 1], Wp[(k + 1) * 512], a1);
                a2 = fmaf(ya_l[k + 2], Wp[(k + 2) * 512], a2);
                a3 = fmaf(ya_l[k + 3], Wp[(k + 3) * 512], a3);
            }
            hsel[f] = (a0 + a1) + (a2 + a3);
        }
    }
    __syncthreads();

    // decoder GEMV: per-thread column over Wst (coalesced, no shuffle chains)
    if (tid < 160) {
        const float* W = ws + WS_WST + tid;
        float a0 = bsrc[tid], a1 = 0.0f, a2 = 0.0f, a3 = 0.0f;
        for (int f = 0; f < 512; f += 4) {
            a0 = fmaf(hsel[f],     W[f * 160],       a0);
            a1 = fmaf(hsel[f + 1], W[(f + 1) * 160], a1);
            a2 = fmaf(hsel[f + 2], W[(f + 2) * 160], a2);
            a3 = fmaf(hsel[f + 3], W[(f + 3) * 160], a3);
        }
        xext[tid] = (a0 + a1) + (a2 + a3);
    }
    __syncthreads();

    // loss + residual update (wave 0); residuals also to LDS for fused sel
    if (tid < 64) {
        int t0 = lane, t1 = lane + 64;
        float sq;
        {
            float yele = xext[80 - hd + t0];
            float yv = yr_l[t0];
            float keep = (yorig[base + t0] != 0.0f) ? 1.0f : 0.0f;
            float d = yele - yv;
            sq = d * d * keep;
            float ynew = yv - yele;
            float xnew = xr_l[t0] - xele_l[t0];
            yr2[t0] = ynew; xr2[t0] = xnew;
            ws[WS_YRES + base + t0] = ynew;
            ws[WS_XRES + base + t0] = xnew;
        }
        if (t1 < 80) {
            float yele = xext[80 - hd + t1];
            float yv = yr_l[t1];
            float keep = (yorig[base + t1] != 0.0f) ? 1.0f : 0.0f;
            float d = yele - yv;
            sq = fmaf(d * keep, d, sq);
            float ynew = yv - yele;
            float xnew = xr_l[t1] - xele_l[t1];
            yr2[t1] = ynew; xr2[t1] = xnew;
            ws[WS_YRES + base + t1] = ynew;
            ws[WS_XRES + base + t1] = xnew;
        }
        sq = wave_sum(sq);
        if (lane == 0) atomicAdd(&ws[WS_LOSS + it], sq);
    }
    if (it == 4) return;
    __syncthreads();

    // ---- fused selector for next iteration (reads xr2/yr2 from LDS) ----
    if (tid < 64) {
        float a = yr2[lane];
        float v = a * a;
        if (lane < 16) { float u = yr2[64 + lane]; v = fmaf(u, u, v); }
        v = wave_sum(v);
        if (lane == 0) s_ny2 = v;
    }
    __syncthreads();

    if (tid < 159) {
        int s = tid;
        int ilo = (s - 79 > 0) ? s - 79 : 0;
        int ihi = (s < 79) ? s : 79;
        float dot = 0.0f, nx2 = 0.0f;
        for (int i = ilo; i <= ihi; ++i) {
            float xv = xr2[i];
            dot = fmaf(xv, yr2[i - s + 79], dot);
            nx2 = fmaf(xv, xv, nx2);
        }
        float denom = sqrtf(nx2) * sqrtf(s_ny2);
        simS[s] = (denom == 0.0f) ? 0.0f : dot / denom;
    }
    __syncthreads();

    if (tid < 64) {
        int theta;
        {
            float v = simS[lane]; int i = lane;
            { float v2 = simS[lane + 64]; int i2 = lane + 64;
              if (v2 > v || (v2 == v && i2 < i)) { v = v2; i = i2; } }
            if (lane < 31) {
                float v2 = simS[lane + 128]; int i2 = lane + 128;
                if (v2 > v || (v2 == v && i2 < i)) { v = v2; i = i2; }
            }
            theta = wave_argmax(v, i);
        }
        int t0 = lane, t1 = lane + 64;
        int ix0 = theta + t0 - 79;
        float ya0 = (ix0 >= 0 && ix0 < 80) ? xr2[ix0] : 0.0f;
        float z0 = ya0 * yr2[t0] / 0.7f;
        float ya1 = 0.0f, z1 = -INFINITY;
        if (t1 < 80) {
            int ix1 = theta + t1 - 79;
            ya1 = (ix1 >= 0 && ix1 < 80) ? xr2[ix1] : 0.0f;
            z1 = ya1 * yr2[t1] / 0.7f;
        }
        float m = wave_max(fmaxf(z0, z1));
        float e0 = expf(z0 - m);
        float e1 = (t1 < 80) ? expf(z1 - m) : 0.0f;
        float S = wave_sum(e0 + e1);
        ya_n[t0] = ya0 * (e0 / S);
        if (t1 < 80) ya_n[t1] = ya1 * (e1 / S);
        ws[WS_YA + p * 88 + t0] = ya_n[t0];
        if (t1 < 80) ws[WS_YA + p * 88 + t1] = ya_n[t1];
        if (lane < 8) ws[WS_YA + p * 88 + 80 + lane] = 0.0f;
        int k0 = 79 - theta + t0;
        ws[WS_XELE + base + t0] = (k0 >= 0 && k0 < 80) ? ya_n[k0] : 0.0f;
        if (t1 < 80) {
            int k1 = 79 - theta + t1;
            ws[WS_XELE + base + t1] = (k1 >= 0 && k1 < 80) ? ya_n[k1] : 0.0f;
        }
    }
}

__global__ void k_final(const float* __restrict__ ws, float* __restrict__ out) {
    float K = ws[WS_K];
    if (K < 1.0f) K = 1.0f;
    out[0] = (ws[WS_LOSS] + ws[WS_LOSS + 1] + ws[WS_LOSS + 2] +
              ws[WS_LOSS + 3] + ws[WS_LOSS + 4]) / (K * 5.0f);
}

extern "C" void kernel_launch(void* const* d_in, const int* in_sizes, int n_in,
                              void* d_out, int out_size, void* d_ws, size_t ws_size,
                              hipStream_t stream) {
    const float* x    = (const float*)d_in[0];
    const float* y    = (const float*)d_in[1];
    const float* Wenc = (const float*)d_in[2];
    const float* benc = (const float*)d_in[3];
    const float* Wsrc = (const float*)d_in[4];
    const float* bsrc = (const float*)d_in[5];
    float* ws  = (float*)d_ws;
    float* out = (float*)d_out;

    k_init<<<320, 256, 0, stream>>>(x, y, Wenc, Wsrc, ws);
    k_cnt<<<320, 256, 0, stream>>>(y, ws);
    k_pre<<<161, 256, 0, stream>>>(Wenc, benc, ws);
    k_sel<<<1024, 128, 0, stream>>>(ws);
    for (int it = 0; it < 5; ++it) {
        k_conv<<<81 * 16, 256, 0, stream>>>(ws);
        k_fuse<<<1024, 256, 0, stream>>>(y, benc, bsrc, ws, it);
    }
    k_final<<<1, 1, 0, stream>>>(ws, out);
}

// Round 9
// 466.083 us; speedup vs baseline: 2.6190x; 1.0855x over previous
//
#include <hip/hip_runtime.h>

// Net_17532056502451 round 9: composite decoder matrix M = Wsrc*Wenc (exact),
// lane-per-position Gram conv with y in static registers + uniform G broadcasts.
//
// ws layout (floats):
#define WS_XRES   0
#define WS_YRES   81920
#define WS_WT     163840   // Wt[c*512+f] = W_enc[f*160+c]
#define WS_MT     245760   // Mt[c*160+o] = sum_f Wsrc[o,f] Wenc[f,c]  (160x160)
#define WS_D0     271360   // d0[o] = sum_f Wsrc[o,f] benc[f]          (160)
#define WS_G      327680   // G padded [160][164]
#define WS_U      353920   // u[160]
#define WS_BB     354080
#define WS_K      354081
#define WS_LOSS   354082   // 5 raw sq-sums (atomic)
#define WS_YA     354088   // [1024][88]
#define WS_XELE   444200   // [1024][80]
#define WS_EN     526120   // [1024][84]

#define GPITCH 164

__global__ void k_init(const float* __restrict__ x, const float* __restrict__ y,
                       const float* __restrict__ Wenc, float* __restrict__ ws) {
    int i = blockIdx.x * 256 + threadIdx.x;   // covers 81920
    ws[WS_XRES + i] = x[i];
    ws[WS_YRES + i] = y[i];
    int f = i / 160, c = i - f * 160;
    ws[WS_WT + c * 512 + f] = Wenc[i];
    if (i == 0) {
        ws[WS_K] = 0.0f;
        for (int t = 0; t < 5; ++t) ws[WS_LOSS + t] = 0.0f;
    }
}

__device__ __forceinline__ float wave_sum(float v) {
    for (int d = 32; d > 0; d >>= 1) v += __shfl_down(v, d);
    return __shfl(v, 0);
}
__device__ __forceinline__ float wave_max(float v) {
    for (int d = 32; d > 0; d >>= 1) v = fmaxf(v, __shfl_down(v, d));
    return __shfl(v, 0);
}
__device__ __forceinline__ int wave_argmax(float v, int i) {
    for (int d = 32; d > 0; d >>= 1) {
        float v2 = __shfl_down(v, d);
        int   i2 = __shfl_down(i, d);
        if (v2 > v || (v2 == v && i2 < i)) { v = v2; i = i2; }
    }
    return __shfl(i, 0);
}

__global__ __launch_bounds__(256)
void k_cnt(const float* __restrict__ y, float* __restrict__ ws) {
    __shared__ int red[256];
    int tid = threadIdx.x;
    int i = blockIdx.x * 256 + tid;
    red[tid] = (y[i] != 0.0f) ? 1 : 0;
    __syncthreads();
    for (int s = 128; s > 0; s >>= 1) {
        if (tid < s) red[tid] += red[tid + s];
        __syncthreads();
    }
    if (tid == 0) atomicAdd(&ws[WS_K], (float)red[0]);
}

// G rows (b<160) / u+bb (b==160): per-thread column, coalesced Wenc reads.
__global__ __launch_bounds__(256)
void k_pre(const float* __restrict__ Wenc, const float* __restrict__ benc,
           float* __restrict__ ws) {
    const int b = blockIdx.x, tid = threadIdx.x;
    __shared__ float wr[512];
    if (b < 160) {
        wr[tid] = ws[WS_WT + b * 512 + tid];
        wr[tid + 256] = ws[WS_WT + b * 512 + 256 + tid];
        __syncthreads();
        if (tid < 160) {
            const float* Wc = Wenc + tid;
            float a0 = 0.f, a1 = 0.f, a2 = 0.f, a3 = 0.f;
            for (int f = 0; f < 512; f += 4) {
                a0 = fmaf(wr[f],     Wc[f * 160],       a0);
                a1 = fmaf(wr[f + 1], Wc[(f + 1) * 160], a1);
                a2 = fmaf(wr[f + 2], Wc[(f + 2) * 160], a2);
                a3 = fmaf(wr[f + 3], Wc[(f + 3) * 160], a3);
            }
            ws[WS_G + b * GPITCH + tid] = (a0 + a1) + (a2 + a3);
        }
    } else {
        wr[tid] = benc[tid];
        wr[tid + 256] = benc[tid + 256];
        __syncthreads();
        if (tid < 160) {
            const float* Wc = Wenc + tid;
            float a0 = 0.f, a1 = 0.f, a2 = 0.f, a3 = 0.f;
            for (int f = 0; f < 512; f += 4) {
                a0 = fmaf(wr[f],     Wc[f * 160],       a0);
                a1 = fmaf(wr[f + 1], Wc[(f + 1) * 160], a1);
                a2 = fmaf(wr[f + 2], Wc[(f + 2) * 160], a2);
                a3 = fmaf(wr[f + 3], Wc[(f + 3) * 160], a3);
            }
            ws[WS_U + tid] = (a0 + a1) + (a2 + a3);
        }
        if (tid < 64) {
            float a = 0.0f;
#pragma unroll
            for (int jj = 0; jj < 8; ++jj) {
                float bv = wr[tid + 64 * jj];
                a = fmaf(bv, bv, a);
            }
            a = wave_sum(a);
            if (tid == 0) ws[WS_BB] = a;
        }
    }
}

// Mt[c][o] = sum_f Wsrc[o,f] Wenc[f,c]; d0[o] = sum_f Wsrc[o,f] benc[f]
__global__ __launch_bounds__(256)
void k_preM(const float* __restrict__ Wenc, const float* __restrict__ benc,
            const float* __restrict__ Wsrc, float* __restrict__ ws) {
    const int o = blockIdx.x, tid = threadIdx.x;
    __shared__ float wr[512];
    wr[tid] = Wsrc[o * 512 + tid];
    wr[tid + 256] = Wsrc[o * 512 + 256 + tid];
    __syncthreads();
    if (tid < 160) {
        const float* Wc = Wenc + tid;
        float a0 = 0.f, a1 = 0.f, a2 = 0.f, a3 = 0.f;
        for (int f = 0; f < 512; f += 4) {
            a0 = fmaf(wr[f],     Wc[f * 160],       a0);
            a1 = fmaf(wr[f + 1], Wc[(f + 1) * 160], a1);
            a2 = fmaf(wr[f + 2], Wc[(f + 2) * 160], a2);
            a3 = fmaf(wr[f + 3], Wc[(f + 3) * 160], a3);
        }
        ws[WS_MT + tid * 160 + o] = (a0 + a1) + (a2 + a3);
    }
    if (tid < 64) {
        float a = 0.0f;
#pragma unroll
        for (int jj = 0; jj < 8; ++jj)
            a = fmaf(wr[tid + 64 * jj], benc[tid + 64 * jj], a);
        a = wave_sum(a);
        if (tid == 0) ws[WS_D0 + o] = a;
    }
}

// ---------------- k_sel: initial selector + softmax per position ----------------
__global__ __launch_bounds__(128)
void k_sel(float* __restrict__ ws) {
    const int p = blockIdx.x, tid = threadIdx.x, lane = tid & 63;
    const int base = p * 80;
    __shared__ float xr[80], yr[80], simS[160], ya[88];
    __shared__ float s_ny2;

    if (tid < 80) { xr[tid] = ws[WS_XRES + base + tid]; yr[tid] = ws[WS_YRES + base + tid]; }
    __syncthreads();

    if (tid < 64) {
        float a = yr[lane];
        float v = a * a;
        if (lane < 16) { float u = yr[64 + lane]; v = fmaf(u, u, v); }
        v = wave_sum(v);
        if (lane == 0) s_ny2 = v;
    }
    __syncthreads();

    for (int s = tid; s < 159; s += 128) {
        int ilo = (s - 79 > 0) ? s - 79 : 0;
        int ihi = (s < 79) ? s : 79;
        float dot = 0.0f, nx2 = 0.0f;
        for (int i = ilo; i <= ihi; ++i) {
            float xv = xr[i];
            dot = fmaf(xv, yr[i - s + 79], dot);
            nx2 = fmaf(xv, xv, nx2);
        }
        float denom = sqrtf(nx2) * sqrtf(s_ny2);
        simS[s] = (denom == 0.0f) ? 0.0f : dot / denom;
    }
    __syncthreads();

    if (tid < 64) {
        int theta;
        {
            float v = simS[lane]; int i = lane;
            { float v2 = simS[lane + 64]; int i2 = lane + 64;
              if (v2 > v || (v2 == v && i2 < i)) { v = v2; i = i2; } }
            if (lane < 31) {
                float v2 = simS[lane + 128]; int i2 = lane + 128;
                if (v2 > v || (v2 == v && i2 < i)) { v = v2; i = i2; }
            }
            theta = wave_argmax(v, i);
        }
        int t0 = lane, t1 = lane + 64;
        int ix0 = theta + t0 - 79;
        float ya0 = (ix0 >= 0 && ix0 < 80) ? xr[ix0] : 0.0f;
        float z0 = ya0 * yr[t0] / 0.7f;
        float ya1 = 0.0f, z1 = -INFINITY;
        if (t1 < 80) {
            int ix1 = theta + t1 - 79;
            ya1 = (ix1 >= 0 && ix1 < 80) ? xr[ix1] : 0.0f;
            z1 = ya1 * yr[t1] / 0.7f;
        }
        float m = wave_max(fmaxf(z0, z1));
        float e0 = expf(z0 - m);
        float e1 = (t1 < 80) ? expf(z1 - m) : 0.0f;
        float S = wave_sum(e0 + e1);
        ya[t0] = ya0 * (e0 / S);
        if (t1 < 80) ya[t1] = ya1 * (e1 / S);
        ws[WS_YA + p * 88 + t0] = ya[t0];
        if (t1 < 80) ws[WS_YA + p * 88 + t1] = ya[t1];
        if (lane < 8) ws[WS_YA + p * 88 + 80 + lane] = 0.0f;
        int k0 = 79 - theta + t0;
        ws[WS_XELE + base + t0] = (k0 >= 0 && k0 < 80) ? ya[k0] : 0.0f;
        if (t1 < 80) {
            int k1 = 79 - theta + t1;
            ws[WS_XELE + base + t1] = (k1 >= 0 && k1 < 80) ? ya[k1] : 0.0f;
        }
    }
}

// ---------------- k_conv: lane = position, uniform G broadcasts ----------------
// Gs[r][j] = G[c0+r][(c0-U)+j]  (aligned copy). v_k = sum_j Gs[k][U+j]*y[j].
template<int U>
__device__ __forceinline__ float conv_w(const float* __restrict__ Gs,
                                        const float* __restrict__ u_l,
                                        const float* __restrict__ y_l,
                                        const float4 (&y4)[20],
                                        int tk0, int pl) {
    constexpr int TMAX = (U == 0) ? 20 : 21;
    float e = 0.0f;
    for (int tkr = 0; tkr < 10; ++tkr) {
        const int tk = tk0 + tkr;
        const int kb = 4 * tk;
        float v[4] = {0.f, 0.f, 0.f, 0.f};
        const float* g0p = Gs + kb * 84;
        const float* g1p = g0p + 84;
        const float* g2p = g0p + 168;
        const float* g3p = g0p + 252;
#pragma unroll
        for (int t = 0; t < TMAX; ++t) {
            float4 ga = *(const float4*)(g0p + 4 * t);
            float4 gb = *(const float4*)(g1p + 4 * t);
            float4 gc = *(const float4*)(g2p + 4 * t);
            float4 gd = *(const float4*)(g3p + 4 * t);
            const float a[4] = {ga.x, ga.y, ga.z, ga.w};
            const float b[4] = {gb.x, gb.y, gb.z, gb.w};
            const float c[4] = {gc.x, gc.y, gc.z, gc.w};
            const float d[4] = {gd.x, gd.y, gd.z, gd.w};
#pragma unroll
            for (int q = 0; q < 4; ++q) {
                const int je = 4 * t + q - U;              // constant after unroll
                if (je >= 0 && je <= 79) {
                    const int th = je >> 2, qh = je & 3;   // static
                    const float yv = (qh == 0) ? y4[th].x : (qh == 1) ? y4[th].y
                                   : (qh == 2) ? y4[th].z : y4[th].w;
                    v[0] = fmaf(a[q], yv, v[0]);
                    v[1] = fmaf(b[q], yv, v[1]);
                    v[2] = fmaf(c[q], yv, v[2]);
                    v[3] = fmaf(d[q], yv, v[3]);
                }
            }
        }
        float4 u4 = *(const float4*)(u_l + kb);
        const float uu[4] = {u4.x, u4.y, u4.z, u4.w};
#pragma unroll
        for (int q = 0; q < 4; ++q) {
            float yk = y_l[pl * 85 + kb + q];
            e = fmaf(yk, v[q] + 2.0f * uu[q], e);
        }
    }
    return e;
}

__global__ __launch_bounds__(128)
void k_conv(float* __restrict__ ws) {
    const int bid = blockIdx.x;       // 81 * 16
    const int s   = bid >> 4;
    const int pg  = bid & 15;
    const int c0  = 80 - s;
    const int U   = c0 & 3;
    const int tid = threadIdx.x;
    const int pl  = tid & 63;         // position lane
    const int wv  = tid >> 6;         // 0/1 : k-half
    const int pbase = pg * 64;

    __shared__ __align__(16) float Gs[80 * 84];
    __shared__ float u_l[80];
    __shared__ float y_l[64 * 85];
    __shared__ float e_l[128];

    {   // stage G (aligned b128 copies), u (shifted), y (pitch-85 scalar)
        const float* src = ws + WS_G + c0 * GPITCH + (c0 - U);
        for (int idx = tid; idx < 1680; idx += 128) {
            int r = idx / 21, m = idx - r * 21;
            *(float4*)(Gs + r * 84 + 4 * m) = *(const float4*)(src + r * GPITCH + 4 * m);
        }
        if (tid < 80) u_l[tid] = ws[WS_U + c0 + tid];
        for (int i = tid; i < 5120; i += 128) {
            int p = i / 80, k = i - p * 80;
            y_l[p * 85 + k] = ws[WS_YA + (pbase + p) * 88 + k];
        }
    }
    // y registers (20 float4, static)
    float4 y4[20];
    {
        const float* yp = ws + WS_YA + (pbase + pl) * 88;
#pragma unroll
        for (int t = 0; t < 20; ++t) y4[t] = *(const float4*)(yp + 4 * t);
    }
    __syncthreads();

    float e;
    switch (U) {
        case 0: e = conv_w<0>(Gs, u_l, y_l, y4, wv * 10, pl); break;
        case 1: e = conv_w<1>(Gs, u_l, y_l, y4, wv * 10, pl); break;
        case 2: e = conv_w<2>(Gs, u_l, y_l, y4, wv * 10, pl); break;
        default: e = conv_w<3>(Gs, u_l, y_l, y4, wv * 10, pl); break;
    }
    e_l[tid] = e;
    __syncthreads();
    if (tid < 64)
        ws[WS_EN + (pbase + tid) * 84 + s] = ws[WS_BB] + e_l[tid] + e_l[tid + 64];
}

// -------- k_fuse: argmax + M-GEMV + loss + residuals + next-iter sel --------
__global__ __launch_bounds__(256)
void k_fuse(const float* __restrict__ yorig, const float* __restrict__ bsrc,
            float* __restrict__ ws, int it) {
    const int p = blockIdx.x, tid = threadIdx.x;
    const int lane = tid & 63;
    const int base = p * 80;

    __shared__ float ya_l[84], yr_l[80], xr_l[80], xele_l[80];
    __shared__ float xext[160];
    __shared__ float yr2[80], xr2[80], simS[160], ya_n[88];
    __shared__ float s_ny2;
    __shared__ int s_hind;

    if (tid < 84) ya_l[tid] = ws[WS_YA + p * 88 + tid];
    if (tid >= 96 && tid < 176) yr_l[tid - 96] = ws[WS_YRES + base + tid - 96];
    if (tid >= 176) xr_l[tid - 176] = ws[WS_XRES + base + tid - 176];
    if (tid < 80) xele_l[tid] = ws[WS_XELE + base + tid];
    __syncthreads();

    if (tid < 64) {
        float v = ws[WS_EN + p * 84 + lane]; int i = lane;
        if (lane < 17) {
            float v2 = ws[WS_EN + p * 84 + lane + 64]; int i2 = lane + 64;
            if (v2 > v || (v2 == v && i2 < i)) { v = v2; i = i2; }
        }
        int hind = wave_argmax(v, i);
        if (lane == 0) s_hind = hind;
    }
    __syncthreads();
    const int hd = s_hind;
    const int cb = 80 - hd;

    // xext[o] = bsrc[o] + d0[o] + sum_k ya[k]*Mt[(cb+k)*160+o]
    if (tid < 160) {
        const float* M = ws + WS_MT + cb * 160 + tid;
        float a0 = bsrc[tid] + ws[WS_D0 + tid], a1 = 0.f, a2 = 0.f, a3 = 0.f;
        for (int k = 0; k < 80; k += 4) {
            a0 = fmaf(ya_l[k],     M[k * 160],       a0);
            a1 = fmaf(ya_l[k + 1], M[(k + 1) * 160], a1);
            a2 = fmaf(ya_l[k + 2], M[(k + 2) * 160], a2);
            a3 = fmaf(ya_l[k + 3], M[(k + 3) * 160], a3);
        }
        xext[tid] = (a0 + a1) + (a2 + a3);
    }
    __syncthreads();

    // loss + residual update (wave 0); residuals also to LDS for fused sel
    if (tid < 64) {
        int t0 = lane, t1 = lane + 64;
        float sq;
        {
            float yele = xext[80 - hd + t0];
            float yv = yr_l[t0];
            float keep = (yorig[base + t0] != 0.0f) ? 1.0f : 0.0f;
            float d = yele - yv;
            sq = d * d * keep;
            float ynew = yv - yele;
            float xnew = xr_l[t0] - xele_l[t0];
            yr2[t0] = ynew; xr2[t0] = xnew;
            ws[WS_YRES + base + t0] = ynew;
            ws[WS_XRES + base + t0] = xnew;
        }
        if (t1 < 80) {
            float yele = xext[80 - hd + t1];
            float yv = yr_l[t1];
            float keep = (yorig[base + t1] != 0.0f) ? 1.0f : 0.0f;
            float d = yele - yv;
            sq = fmaf(d * keep, d, sq);
            float ynew = yv - yele;
            float xnew = xr_l[t1] - xele_l[t1];
            yr2[t1] = ynew; xr2[t1] = xnew;
            ws[WS_YRES + base + t1] = ynew;
            ws[WS_XRES + base + t1] = xnew;
        }
        sq = wave_sum(sq);
        if (lane == 0) atomicAdd(&ws[WS_LOSS + it], sq);
    }
    if (it == 4) return;
    __syncthreads();

    // ---- fused selector for next iteration ----
    if (tid < 64) {
        float a = yr2[lane];
        float v = a * a;
        if (lane < 16) { float u = yr2[64 + lane]; v = fmaf(u, u, v); }
        v = wave_sum(v);
        if (lane == 0) s_ny2 = v;
    }
    __syncthreads();

    if (tid < 159) {
        int s = tid;
        int ilo = (s - 79 > 0) ? s - 79 : 0;
        int ihi = (s < 79) ? s : 79;
        float dot = 0.0f, nx2 = 0.0f;
        for (int i = ilo; i <= ihi; ++i) {
            float xv = xr2[i];
            dot = fmaf(xv, yr2[i - s + 79], dot);
            nx2 = fmaf(xv, xv, nx2);
        }
        float denom = sqrtf(nx2) * sqrtf(s_ny2);
        simS[s] = (denom == 0.0f) ? 0.0f : dot / denom;
    }
    __syncthreads();

    if (tid < 64) {
        int theta;
        {
            float v = simS[lane]; int i = lane;
            { float v2 = simS[lane + 64]; int i2 = lane + 64;
              if (v2 > v || (v2 == v && i2 < i)) { v = v2; i = i2; } }
            if (lane < 31) {
                float v2 = simS[lane + 128]; int i2 = lane + 128;
                if (v2 > v || (v2 == v && i2 < i)) { v = v2; i = i2; }
            }
            theta = wave_argmax(v, i);
        }
        int t0 = lane, t1 = lane + 64;
        int ix0 = theta + t0 - 79;
        float ya0 = (ix0 >= 0 && ix0 < 80) ? xr2[ix0] : 0.0f;
        float z0 = ya0 * yr2[t0] / 0.7f;
        float ya1 = 0.0f, z1 = -INFINITY;
        if (t1 < 80) {
            int ix1 = theta + t1 - 79;
            ya1 = (ix1 >= 0 && ix1 < 80) ? xr2[ix1] : 0.0f;
            z1 = ya1 * yr2[t1] / 0.7f;
        }
        float m = wave_max(fmaxf(z0, z1));
        float e0 = expf(z0 - m);
        float e1 = (t1 < 80) ? expf(z1 - m) : 0.0f;
        float S = wave_sum(e0 + e1);
        ya_n[t0] = ya0 * (e0 / S);
        if (t1 < 80) ya_n[t1] = ya1 * (e1 / S);
        ws[WS_YA + p * 88 + t0] = ya_n[t0];
        if (t1 < 80) ws[WS_YA + p * 88 + t1] = ya_n[t1];
        if (lane < 8) ws[WS_YA + p * 88 + 80 + lane] = 0.0f;
        int k0 = 79 - theta + t0;
        ws[WS_XELE + base + t0] = (k0 >= 0 && k0 < 80) ? ya_n[k0] : 0.0f;
        if (t1 < 80) {
            int k1 = 79 - theta + t1;
            ws[WS_XELE + base + t1] = (k1 >= 0 && k1 < 80) ? ya_n[k1] : 0.0f;
        }
    }
}

__global__ void k_final(const float* __restrict__ ws, float* __restrict__ out) {
    float K = ws[WS_K];
    if (K < 1.0f) K = 1.0f;
    out[0] = (ws[WS_LOSS] + ws[WS_LOSS + 1] + ws[WS_LOSS + 2] +
              ws[WS_LOSS + 3] + ws[WS_LOSS + 4]) / (K * 5.0f);
}

extern "C" void kernel_launch(void* const* d_in, const int* in_sizes, int n_in,
                              void* d_out, int out_size, void* d_ws, size_t ws_size,
                              hipStream_t stream) {
    const float* x    = (const float*)d_in[0];
    const float* y    = (const float*)d_in[1];
    const float* Wenc = (const float*)d_in[2];
    const float* benc = (const float*)d_in[3];
    const float* Wsrc = (const float*)d_in[4];
    const float* bsrc = (const float*)d_in[5];
    float* ws  = (float*)d_ws;
    float* out = (float*)d_out;

    k_init<<<320, 256, 0, stream>>>(x, y, Wenc, ws);
    k_cnt<<<320, 256, 0, stream>>>(y, ws);
    k_pre<<<161, 256, 0, stream>>>(Wenc, benc, ws);
    k_preM<<<160, 256, 0, stream>>>(Wenc, benc, Wsrc, ws);
    k_sel<<<1024, 128, 0, stream>>>(ws);
    for (int it = 0; it < 5; ++it) {
        k_conv<<<81 * 16, 128, 0, stream>>>(ws);
        k_fuse<<<1024, 256, 0, stream>>>(y, bsrc, ws, it);
    }
    k_final<<<1, 1, 0, stream>>>(ws, out);
}